// Round 2
// baseline (252.561 us; speedup 1.0000x reference)
//
#include <hip/hip_runtime.h>
#include <hip/hip_cooperative_groups.h>
#include <stdint.h>

// FP4 quant-dequant, faithful to the JAX reference in float32 arithmetic.
// v4: single cooperative kernel, STATELESS across grid.sync().
// v3 post-mortem: holding x in registers across the sync spilled all 64
// data VGPRs to scratch (VGPR_Count=56 < 64 needed) -> 114 us latency-bound.
// v4 phase 1 computes scales only; phase 2 re-reads x from L3 (FETCH=33MB in
// v3 proves x is L3-resident) with coalesced float4 loads. No live state
// across the sync -> no spill. Numerics bit-identical to v2/v3 (exact
// order-independent top-5; deterministic redundant smin/smax reduce).
// Falls back to the verified v2 3-kernel path if coop occupancy/launch fails.

#define BLK 64
#define WG 256
#define MAX_COOP_WGS 2048
#define FLT_BIG 3.402823466e+38f

namespace cg = cooperative_groups;

// Branchless insert of `a` into descending-sorted top-5 register array.
__device__ __forceinline__ void ins5(float (&t)[5], float a) {
#pragma unroll
    for (int k = 0; k < 4; ++k) {
        float m = fmaxf(t[k], a);
        a = fminf(t[k], a);
        t[k] = m;
    }
    t[4] = fmaxf(t[4], a);
}

// JAX f32 quantile: q = 0.95f*63.0f; result = v59*lw + v60*hw
__device__ __forceinline__ float quantile5(const float (&A)[5]) {
    const float qs = 0.95f * 63.0f;      // 59.849998474121094f
    const float hw = qs - 59.0f;
    const float lw = 60.0f - qs;
    // A[3] = 4th largest = sorted v[60]; A[4] = 5th largest = v[59]
    float s = __fadd_rn(__fmul_rn(A[4], lw), __fmul_rn(A[3], hw));
    return fmaxf(s, 1e-8f);
}

// Nearest FP4 level via boundary ladder (exact dyadics; ties match argmin).
__device__ __forceinline__ float qlevel(float xn) {
    float bv = -3.0f;
    bv += (xn > -2.5f)   ? 1.0f  : 0.0f;
    bv += (xn > -1.75f)  ? 0.5f  : 0.0f;
    bv += (xn > -1.25f)  ? 0.5f  : 0.0f;
    bv += (xn > -0.875f) ? 0.25f : 0.0f;
    bv += (xn > -0.375f) ? 0.75f : 0.0f;
    bv += (xn > 0.375f)  ? 0.75f : 0.0f;
    bv += (xn > 0.875f)  ? 0.25f : 0.0f;
    bv += (xn > 1.25f)   ? 0.5f  : 0.0f;
    bv += (xn > 1.75f)   ? 0.5f  : 0.0f;
    bv += (xn > 2.5f)    ? 1.0f  : 0.0f;
    return bv;
}

// ---------------- Fused cooperative kernel (stateless phases) ----------------
// Phase 1 task j covers elements [16j, 16j+16). task = k*T + t, so tasks
// 4b..4b+3 sit in an aligned 4-lane group of one wave -> block b owned by
// that group; top-5 merged with 2 shfl_xor steps (exact, order-independent).
__global__ __launch_bounds__(WG, 4) void k_fused(const float* __restrict__ x,
                                                 int n, int nblocks,
                                                 float* __restrict__ out,
                                                 float* __restrict__ scales,
                                                 float* __restrict__ partMin,
                                                 float* __restrict__ partMax) {
    const int T = (int)gridDim.x * WG;
    const int t = (int)blockIdx.x * WG + (int)threadIdx.x;
    const int lane = (int)threadIdx.x & 63;
    const int w = (int)threadIdx.x >> 6;
    __shared__ float smn[4], smx[4];

    // ---------- Phase 1: per-block scales; nothing kept for phase 2 ----------
    float mn = FLT_BIG, mx = 0.0f;
    const int ntasks = nblocks << 2;         // 16-elem tasks (multiple of 4)
    for (int task = t; task < ntasks; task += T) {
        const int base = task << 4;
        float4 v[4];
        if (base + 16 <= n) {
            const float4* x4 = reinterpret_cast<const float4*>(x + base);
#pragma unroll
            for (int q = 0; q < 4; ++q) v[q] = x4[q];
        } else {
#pragma unroll
            for (int q = 0; q < 4; ++q) {
                const int i0 = base + q * 4;
                v[q].x = (i0 + 0 < n) ? x[i0 + 0] : 0.0f;  // reference zero-pads
                v[q].y = (i0 + 1 < n) ? x[i0 + 1] : 0.0f;
                v[q].z = (i0 + 2 < n) ? x[i0 + 2] : 0.0f;
                v[q].w = (i0 + 3 < n) ? x[i0 + 3] : 0.0f;
            }
        }
        // Two insertion chains for ILP; abs>=0 so 0-init is safe.
        float A[5] = {0.f, 0.f, 0.f, 0.f, 0.f};
        float B[5] = {0.f, 0.f, 0.f, 0.f, 0.f};
#pragma unroll
        for (int q = 0; q < 4; q += 2) {
            ins5(A, fabsf(v[q].x));     ins5(B, fabsf(v[q + 1].x));
            ins5(A, fabsf(v[q].y));     ins5(B, fabsf(v[q + 1].y));
            ins5(A, fabsf(v[q].z));     ins5(B, fabsf(v[q + 1].z));
            ins5(A, fabsf(v[q].w));     ins5(B, fabsf(v[q + 1].w));
        }
#pragma unroll
        for (int k = 0; k < 5; ++k) ins5(A, B[k]);
        // Merge top-5 lists across the aligned 4-lane group (block = 64 elems).
#pragma unroll
        for (int m = 1; m <= 2; m <<= 1) {
            float o0 = __shfl_xor(A[0], m, 64);
            float o1 = __shfl_xor(A[1], m, 64);
            float o2 = __shfl_xor(A[2], m, 64);
            float o3 = __shfl_xor(A[3], m, 64);
            float o4 = __shfl_xor(A[4], m, 64);
            ins5(A, o0); ins5(A, o1); ins5(A, o2); ins5(A, o3); ins5(A, o4);
        }
        const float s = quantile5(A);
        // All 4 lanes hold identical s: fmin/fmax are idempotent, store once.
        mn = fminf(mn, s);
        mx = fmaxf(mx, s);
        if ((task & 3) == 0) scales[task >> 2] = s;
    }

    // Per-WG min/max partials (task-less threads contribute neutral values).
#pragma unroll
    for (int off = 32; off > 0; off >>= 1) {
        mn = fminf(mn, __shfl_xor(mn, off, 64));
        mx = fmaxf(mx, __shfl_xor(mx, off, 64));
    }
    if (lane == 0) { smn[w] = mn; smx[w] = mx; }
    __syncthreads();
    if (threadIdx.x == 0) {
        float fmn = smn[0], fmx = smx[0];
#pragma unroll
        for (int i = 1; i < 4; ++i) { fmn = fminf(fmn, smn[i]); fmx = fmaxf(fmx, smx[i]); }
        partMin[blockIdx.x] = fmn;
        partMax[blockIdx.x] = fmx;
    }

    cg::this_grid().sync();   // no live VGPR state crosses this point

    // ---------- Redundant per-WG reduce of gridDim partials (L2-hot) ----------
    // Same deterministic order in every WG -> bit-identical smin/smax.
    float gmn = FLT_BIG, gmx = 0.0f;
    for (int i = (int)threadIdx.x; i < (int)gridDim.x; i += WG) {
        gmn = fminf(gmn, partMin[i]);
        gmx = fmaxf(gmx, partMax[i]);
    }
#pragma unroll
    for (int off = 32; off > 0; off >>= 1) {
        gmn = fminf(gmn, __shfl_xor(gmn, off, 64));
        gmx = fmaxf(gmx, __shfl_xor(gmx, off, 64));
    }
    if (lane == 0) { smn[w] = gmn; smx[w] = gmx; }
    __syncthreads();
    const float smin = fminf(fminf(smn[0], smn[1]), fminf(smn[2], smn[3]));
    const float smax = fmaxf(fmaxf(smx[0], smx[1]), fmaxf(smx[2], smx[3]));

    // ---------- Phase 2: coalesced re-read of x (L3-hot) + quantize ----------
    const bool  cond = (smax > smin);
    const float ss   = cond ? __fdiv_rn(__fsub_rn(smax, smin), 255.0f) : 1.0f;
    const int nf4 = n >> 2;
    for (int i4 = t; i4 < nf4; i4 += T) {
        const int i = i4 << 2;
        const float s = scales[i >> 6];      // 4-aligned group never crosses a block
        float ds;
        if (cond) {
            float q = rintf(__fdiv_rn(__fsub_rn(s, smin), ss));   // round half-even
            q = fminf(fmaxf(q, 0.0f), 255.0f);                    // clip AFTER round
            ds = __fmul_rn(q, ss);
        } else {
            ds = 0.0f;   // q=0, scale_scale=1 -> deq 0
        }
        const float4 xv = *reinterpret_cast<const float4*>(x + i);
        float4 ov;
        ov.x = __fmul_rn(qlevel(__fdiv_rn(xv.x, s)), ds);
        ov.y = __fmul_rn(qlevel(__fdiv_rn(xv.y, s)), ds);
        ov.z = __fmul_rn(qlevel(__fdiv_rn(xv.z, s)), ds);
        ov.w = __fmul_rn(qlevel(__fdiv_rn(xv.w, s)), ds);
        *reinterpret_cast<float4*>(out + i) = ov;
    }
    // Scalar tail (n % 4 elements).
    if (t == 0) {
        for (int i = nf4 << 2; i < n; ++i) {
            const float s = scales[i >> 6];
            float ds;
            if (cond) {
                float q = rintf(__fdiv_rn(__fsub_rn(s, smin), ss));
                q = fminf(fmaxf(q, 0.0f), 255.0f);
                ds = __fmul_rn(q, ss);
            } else {
                ds = 0.0f;
            }
            out[i] = __fmul_rn(qlevel(__fdiv_rn(x[i], s)), ds);
        }
    }
}

// ---------------- v2 fallback path (verified) ----------------
__global__ __launch_bounds__(WG) void k_scales(const float* __restrict__ x,
                                               int n, int nblocks,
                                               float* __restrict__ scales,
                                               float* __restrict__ partMin,
                                               float* __restrict__ partMax) {
    const int b = blockIdx.x * WG + threadIdx.x;
    const bool valid = (b < nblocks);

    float s = 0.0f;
    if (valid) {
        float4 v[16];
        const int base = b * BLK;
        if (base + BLK <= n) {
            const float4* x4 = reinterpret_cast<const float4*>(x + base);
#pragma unroll
            for (int j = 0; j < 16; ++j) v[j] = x4[j];
        } else {
            for (int j = 0; j < 16; ++j) {
                float tmp[4];
                for (int k = 0; k < 4; ++k) {
                    int idx = base + j * 4 + k;
                    tmp[k] = (idx < n) ? x[idx] : 0.0f;
                }
                v[j] = make_float4(tmp[0], tmp[1], tmp[2], tmp[3]);
            }
        }
        float A[5] = {0.f, 0.f, 0.f, 0.f, 0.f};
        float B[5] = {0.f, 0.f, 0.f, 0.f, 0.f};
#pragma unroll
        for (int j = 0; j < 16; j += 2) {
            ins5(A, fabsf(v[j].x));     ins5(B, fabsf(v[j + 1].x));
            ins5(A, fabsf(v[j].y));     ins5(B, fabsf(v[j + 1].y));
            ins5(A, fabsf(v[j].z));     ins5(B, fabsf(v[j + 1].z));
            ins5(A, fabsf(v[j].w));     ins5(B, fabsf(v[j + 1].w));
        }
#pragma unroll
        for (int k = 0; k < 5; ++k) ins5(A, B[k]);
        s = quantile5(A);
        scales[b] = s;
    }

    float mn = valid ? s : FLT_BIG;
    float mx = valid ? s : 0.0f;
#pragma unroll
    for (int off = 32; off > 0; off >>= 1) {
        mn = fminf(mn, __shfl_xor(mn, off, 64));
        mx = fmaxf(mx, __shfl_xor(mx, off, 64));
    }
    __shared__ float smn[4], smx[4];
    const int lane = threadIdx.x & 63, w = threadIdx.x >> 6;
    if (lane == 0) { smn[w] = mn; smx[w] = mx; }
    __syncthreads();
    if (threadIdx.x == 0) {
        float fmn = smn[0], fmx = smx[0];
#pragma unroll
        for (int i = 1; i < 4; ++i) { fmn = fminf(fmn, smn[i]); fmx = fmaxf(fmx, smx[i]); }
        partMin[blockIdx.x] = fmn;
        partMax[blockIdx.x] = fmx;
    }
}

__global__ __launch_bounds__(WG) void k_reduce(const float* __restrict__ partMin,
                                               const float* __restrict__ partMax,
                                               int nparts,
                                               float* __restrict__ hdr) {
    float mn = FLT_BIG, mx = 0.0f;
    for (int i = threadIdx.x; i < nparts; i += WG) {
        mn = fminf(mn, partMin[i]);
        mx = fmaxf(mx, partMax[i]);
    }
#pragma unroll
    for (int off = 32; off > 0; off >>= 1) {
        mn = fminf(mn, __shfl_xor(mn, off, 64));
        mx = fmaxf(mx, __shfl_xor(mx, off, 64));
    }
    __shared__ float smn[4], smx[4];
    int lane = threadIdx.x & 63, w = threadIdx.x >> 6;
    if (lane == 0) { smn[w] = mn; smx[w] = mx; }
    __syncthreads();
    if (threadIdx.x == 0) {
        float fmn = smn[0], fmx = smx[0];
#pragma unroll
        for (int i = 1; i < 4; ++i) { fmn = fminf(fmn, smn[i]); fmx = fmaxf(fmx, smx[i]); }
        hdr[0] = fmn; hdr[1] = fmx;
    }
}

__global__ __launch_bounds__(WG) void k_quant(const float* __restrict__ x,
                                              const float* __restrict__ scales,
                                              const float* __restrict__ hdr,
                                              int n,
                                              float* __restrict__ out) {
    const int t = blockIdx.x * WG + threadIdx.x;
    const int i = t * 4;
    if (i >= n) return;

    const float smin = hdr[0], smax = hdr[1];
    const int b = i >> 6;
    const float s = scales[b];

    float ds;
    if (smax > smin) {
        const float ss = __fdiv_rn(__fsub_rn(smax, smin), 255.0f);
        float q = rintf(__fdiv_rn(__fsub_rn(s, smin), ss));
        q = fminf(fmaxf(q, 0.0f), 255.0f);
        ds = __fmul_rn(q, ss);
    } else {
        ds = 0.0f;
    }

    if (i + 3 < n) {
        const float4 xv = *reinterpret_cast<const float4*>(x + i);
        float4 ov;
        ov.x = __fmul_rn(qlevel(__fdiv_rn(xv.x, s)), ds);
        ov.y = __fmul_rn(qlevel(__fdiv_rn(xv.y, s)), ds);
        ov.z = __fmul_rn(qlevel(__fdiv_rn(xv.z, s)), ds);
        ov.w = __fmul_rn(qlevel(__fdiv_rn(xv.w, s)), ds);
        *reinterpret_cast<float4*>(out + i) = ov;
    } else {
        for (int j = 0; j < 4 && i + j < n; ++j)
            out[i + j] = __fmul_rn(qlevel(__fdiv_rn(x[i + j], s)), ds);
    }
}

extern "C" void kernel_launch(void* const* d_in, const int* in_sizes, int n_in,
                              void* d_out, int out_size, void* d_ws, size_t ws_size,
                              hipStream_t stream) {
    const float* x = (const float*)d_in[0];
    float* out = (float*)d_out;
    const int n = in_sizes[0];
    const int nblocks = (n + BLK - 1) / BLK;
    float* ws = (float*)d_ws;

    // ---- cooperative fused path (grid-stride: any n) ----
    static int coopGrid = -2;   // -2 = uninit, 0 = unusable; host-only queries
    if (coopGrid == -2) {
        int nb = 0;
        hipError_t e1 = hipOccupancyMaxActiveBlocksPerMultiprocessor(&nb, k_fused, WG, 0);
        int dev = 0;
        (void)hipGetDevice(&dev);
        hipDeviceProp_t prop;
        hipError_t e2 = hipGetDeviceProperties(&prop, dev);
        if (e1 == hipSuccess && e2 == hipSuccess && prop.cooperativeLaunch && nb > 0) {
            long long g = (long long)nb * prop.multiProcessorCount;
            coopGrid = (int)(g < MAX_COOP_WGS ? g : MAX_COOP_WGS);
        } else {
            coopGrid = 0;
        }
    }
    if (coopGrid > 0 && n > 0) {
        // Don't launch more WGs than phase work (keeps tiny-n launches cheap).
        long long tasks = (long long)nblocks * 4;
        long long quads = (long long)(n >> 2) + 1;
        long long maxWork = (tasks > quads ? tasks : quads);
        long long wgsWanted = (maxWork + WG - 1) / WG;
        int grid = (int)(wgsWanted < coopGrid ? (wgsWanted > 0 ? wgsWanted : 1) : coopGrid);

        float* partMin = ws;                        // MAX_COOP_WGS floats
        float* partMax = ws + MAX_COOP_WGS;         // MAX_COOP_WGS floats
        float* scales  = ws + 2 * MAX_COOP_WGS;     // nblocks floats

        const float* xa = x;
        int na = n, nba = nblocks;
        float* oa = out;
        void* args[] = {(void*)&xa, (void*)&na, (void*)&nba, (void*)&oa,
                        (void*)&scales, (void*)&partMin, (void*)&partMax};
        hipError_t err = hipLaunchCooperativeKernel(k_fused, dim3(grid), dim3(WG),
                                                    args, 0u, stream);
        if (err == hipSuccess) return;
        (void)hipGetLastError();   // clear and fall through to v2 path
    }

    // ---- v2 fallback: 3-kernel path ----
    const int nwgScales = (nblocks + WG - 1) / WG;

    float* scales  = ws;
    float* partMin = ws + nblocks;
    float* partMax = partMin + nwgScales;
    float* hdr     = partMax + nwgScales;

    k_scales<<<nwgScales, WG, 0, stream>>>(x, n, nblocks, scales, partMin, partMax);
    k_reduce<<<1, WG, 0, stream>>>(partMin, partMax, nwgScales, hdr);
    k_quant<<<((n + 3) / 4 + WG - 1) / WG, WG, 0, stream>>>(x, scales, hdr, n, out);
}

// Round 3
// 132.407 us; speedup vs baseline: 1.9075x; 1.9075x over previous
//
#include <hip/hip_runtime.h>
#include <stdint.h>

// FP4 quant-dequant, faithful to the JAX reference in float32 arithmetic.
// v5: back to plain stream kernels (graph-friendly). Post-mortems of v3/v4:
// BOTH cooperative-launch variants ran 5-10x off roofline with ideal HBM
// traffic and idle pipes (v4: VGPR=20, occ 90%, VALU 13%, 620 GB/s) -- the
// coop launch itself degrades the memory path; dropped for good.
// v5 = v2 minus one launch: k_reduce is folded into k_quant2 (every WG
// redundantly reduces <=1024x2 partials from L2 in deterministic order ->
// bit-identical smin/smax), and each quant thread owns 16 consecutive
// elements (quarter block) so the scale double-quantization (div/rint/clip)
// runs once per thread instead of once per float4.

#define BLK 64
#define WG 256
#define FLT_BIG 3.402823466e+38f

// Branchless insert of `a` into descending-sorted top-5 register array.
__device__ __forceinline__ void ins5(float (&t)[5], float a) {
#pragma unroll
    for (int k = 0; k < 4; ++k) {
        float m = fmaxf(t[k], a);
        a = fminf(t[k], a);
        t[k] = m;
    }
    t[4] = fmaxf(t[4], a);
}

// JAX f32 quantile: q = 0.95f*63.0f; result = v59*lw + v60*hw
__device__ __forceinline__ float quantile5(const float (&A)[5]) {
    const float qs = 0.95f * 63.0f;      // 59.849998474121094f
    const float hw = qs - 59.0f;
    const float lw = 60.0f - qs;
    // A[3] = 4th largest = sorted v[60]; A[4] = 5th largest = v[59]
    float s = __fadd_rn(__fmul_rn(A[4], lw), __fmul_rn(A[3], hw));
    return fmaxf(s, 1e-8f);
}

// Nearest FP4 level via boundary ladder (exact dyadics; ties match argmin).
__device__ __forceinline__ float qlevel(float xn) {
    float bv = -3.0f;
    bv += (xn > -2.5f)   ? 1.0f  : 0.0f;
    bv += (xn > -1.75f)  ? 0.5f  : 0.0f;
    bv += (xn > -1.25f)  ? 0.5f  : 0.0f;
    bv += (xn > -0.875f) ? 0.25f : 0.0f;
    bv += (xn > -0.375f) ? 0.75f : 0.0f;
    bv += (xn > 0.375f)  ? 0.75f : 0.0f;
    bv += (xn > 0.875f)  ? 0.25f : 0.0f;
    bv += (xn > 1.25f)   ? 0.5f  : 0.0f;
    bv += (xn > 1.75f)   ? 0.5f  : 0.0f;
    bv += (xn > 2.5f)    ? 1.0f  : 0.0f;
    return bv;
}

// ---------------- Kernel 1: per-block scales + per-WG min/max ----------------
// One thread = one 64-element block (16 independent float4 loads). Verified
// numerics (exact order-independent top-5; JAX-f32 quantile interp).
__global__ __launch_bounds__(WG) void k_scales(const float* __restrict__ x,
                                               int n, int nblocks,
                                               float* __restrict__ scales,
                                               float* __restrict__ partMin,
                                               float* __restrict__ partMax) {
    const int b = blockIdx.x * WG + threadIdx.x;
    const bool valid = (b < nblocks);

    float s = 0.0f;
    if (valid) {
        float4 v[16];
        const int base = b * BLK;
        if (base + BLK <= n) {
            const float4* x4 = reinterpret_cast<const float4*>(x + base);
#pragma unroll
            for (int j = 0; j < 16; ++j) v[j] = x4[j];
        } else {
            for (int j = 0; j < 16; ++j) {
                float tmp[4];
                for (int k = 0; k < 4; ++k) {
                    int idx = base + j * 4 + k;
                    tmp[k] = (idx < n) ? x[idx] : 0.0f;  // reference zero-pads
                }
                v[j] = make_float4(tmp[0], tmp[1], tmp[2], tmp[3]);
            }
        }
        // Two insertion chains for ILP; abs>=0 so 0-init is safe.
        float A[5] = {0.f, 0.f, 0.f, 0.f, 0.f};
        float B[5] = {0.f, 0.f, 0.f, 0.f, 0.f};
#pragma unroll
        for (int j = 0; j < 16; j += 2) {
            ins5(A, fabsf(v[j].x));     ins5(B, fabsf(v[j + 1].x));
            ins5(A, fabsf(v[j].y));     ins5(B, fabsf(v[j + 1].y));
            ins5(A, fabsf(v[j].z));     ins5(B, fabsf(v[j + 1].z));
            ins5(A, fabsf(v[j].w));     ins5(B, fabsf(v[j + 1].w));
        }
#pragma unroll
        for (int k = 0; k < 5; ++k) ins5(A, B[k]);
        s = quantile5(A);
        scales[b] = s;
    }

    // Per-WG scale min/max partials (invalid threads contribute neutral).
    float mn = valid ? s : FLT_BIG;
    float mx = valid ? s : 0.0f;
#pragma unroll
    for (int off = 32; off > 0; off >>= 1) {
        mn = fminf(mn, __shfl_xor(mn, off, 64));
        mx = fmaxf(mx, __shfl_xor(mx, off, 64));
    }
    __shared__ float smn[4], smx[4];
    const int lane = threadIdx.x & 63, w = threadIdx.x >> 6;
    if (lane == 0) { smn[w] = mn; smx[w] = mx; }
    __syncthreads();
    if (threadIdx.x == 0) {
        float fmn = smn[0], fmx = smx[0];
#pragma unroll
        for (int i = 1; i < 4; ++i) { fmn = fminf(fmn, smn[i]); fmx = fmaxf(fmx, smx[i]); }
        partMin[blockIdx.x] = fmn;
        partMax[blockIdx.x] = fmx;
    }
}

// ------------- Kernel 2: redundant smin/smax reduce + quantize -------------
// Stream order guarantees k_scales completed; every WG re-reduces the
// (<=~1024)x2 partials from L2 in the SAME deterministic order -> bit-identical
// smin/smax in all WGs (fmin/fmax are exact & associative here anyway).
// Each thread owns 16 consecutive elements = a quarter of one 64-block, so
// one scales[] read and ONE ds computation per thread.
__global__ __launch_bounds__(WG) void k_quant2(const float* __restrict__ x,
                                               const float* __restrict__ scales,
                                               const float* __restrict__ partMin,
                                               const float* __restrict__ partMax,
                                               int nparts, int n,
                                               float* __restrict__ out) {
    // ---- per-WG global smin/smax ----
    float mn = FLT_BIG, mx = 0.0f;
    for (int i = (int)threadIdx.x; i < nparts; i += WG) {
        mn = fminf(mn, partMin[i]);
        mx = fmaxf(mx, partMax[i]);
    }
#pragma unroll
    for (int off = 32; off > 0; off >>= 1) {
        mn = fminf(mn, __shfl_xor(mn, off, 64));
        mx = fmaxf(mx, __shfl_xor(mx, off, 64));
    }
    __shared__ float smn[4], smx[4];
    const int lane = threadIdx.x & 63, w = threadIdx.x >> 6;
    if (lane == 0) { smn[w] = mn; smx[w] = mx; }
    __syncthreads();
    const float smin = fminf(fminf(smn[0], smn[1]), fminf(smn[2], smn[3]));
    const float smax = fmaxf(fmaxf(smx[0], smx[1]), fmaxf(smx[2], smx[3]));

    // ---- quantize 16 consecutive elements (never crosses a block) ----
    const int t = blockIdx.x * WG + threadIdx.x;
    const int base = t << 4;
    if (base >= n) return;

    const float s = scales[base >> 6];

    // Double-quantization of the scale: once per thread.
    float ds;
    if (smax > smin) {
        const float ss = __fdiv_rn(__fsub_rn(smax, smin), 255.0f);
        float q = rintf(__fdiv_rn(__fsub_rn(s, smin), ss));   // round half-even
        q = fminf(fmaxf(q, 0.0f), 255.0f);                    // clip AFTER round
        ds = __fmul_rn(q, ss);
    } else {
        ds = 0.0f;   // q=0, scale_scale=1 -> deq 0
    }

    if (base + 16 <= n) {
        const float4* x4 = reinterpret_cast<const float4*>(x + base);
        float4* o4 = reinterpret_cast<float4*>(out + base);
        float4 v[4];
#pragma unroll
        for (int j = 0; j < 4; ++j) v[j] = x4[j];   // 4 independent loads in flight
#pragma unroll
        for (int j = 0; j < 4; ++j) {
            float4 ov;
            ov.x = __fmul_rn(qlevel(__fdiv_rn(v[j].x, s)), ds);
            ov.y = __fmul_rn(qlevel(__fdiv_rn(v[j].y, s)), ds);
            ov.z = __fmul_rn(qlevel(__fdiv_rn(v[j].z, s)), ds);
            ov.w = __fmul_rn(qlevel(__fdiv_rn(v[j].w, s)), ds);
            o4[j] = ov;
        }
    } else {
        for (int j = 0; j < 16 && base + j < n; ++j)
            out[base + j] = __fmul_rn(qlevel(__fdiv_rn(x[base + j], s)), ds);
    }
}

extern "C" void kernel_launch(void* const* d_in, const int* in_sizes, int n_in,
                              void* d_out, int out_size, void* d_ws, size_t ws_size,
                              hipStream_t stream) {
    const float* x = (const float*)d_in[0];
    float* out = (float*)d_out;
    const int n = in_sizes[0];
    const int nblocks = (n + BLK - 1) / BLK;          // 262144 for n=16.7M
    const int nwgA = (nblocks + WG - 1) / WG;         // 1024
    const int nthreadsB = (n + 15) / 16;
    const int nwgB = (nthreadsB + WG - 1) / WG;       // 4096

    float* ws = (float*)d_ws;
    float* scales  = ws;                 // nblocks floats
    float* partMin = ws + nblocks;       // nwgA floats
    float* partMax = partMin + nwgA;     // nwgA floats

    k_scales<<<nwgA, WG, 0, stream>>>(x, n, nblocks, scales, partMin, partMax);
    k_quant2<<<nwgB, WG, 0, stream>>>(x, scales, partMin, partMax, nwgA, n, out);
}